// Round 14
// baseline (459.128 us; speedup 1.0000x reference)
//
#include <hip/hip_runtime.h>
#include <hip/hip_fp16.h>

// GCN encoder: 3x (GCNConv + ReLU), dims 256->128->64->32
// N=50000 nodes, E=800000 edges. edge_index delivered as int32 (harness).
// R2: CSR gather.  R4: packed deg+cnt atomic.  R5: fp16 H buffers.
// R6: MFMA gemms.  R7: atomic-free fill via rank.  R10: persistent-B gemm.
// R11: fused scan; pipelined agg.  R12: gemm1 fused with histogram.
// R13: histogram = work-stealing chunk loop (64 edges/wave, global counter)
//      so gemm1 and the atomic wall truly overlap (R12 ran them serial);
//      agg pipeline deepened (pairs 4-ahead, H-rows 3-ahead).

#define D0 256
#define D1 128
#define D2 64
#define D3 32

#define FIX_SCALE 16777216.0f           // 2^24 fixed-point for degree
#define FIX_INV   (1.0f / 16777216.0f)

typedef _Float16 half8 __attribute__((ext_vector_type(8)));
typedef float floatx4 __attribute__((ext_vector_type(4)));

// ------------------------------------------------------ gemm device core ---
template <typename SRC>
__device__ __forceinline__ half8 loadA(const SRC* __restrict__ p) {
    if constexpr (sizeof(SRC) == 4) {
        float4 f0 = *(const float4*)p;
        float4 f1 = *(const float4*)(p + 4);
        half8 v;
        v[0] = (_Float16)f0.x; v[1] = (_Float16)f0.y;
        v[2] = (_Float16)f0.z; v[3] = (_Float16)f0.w;
        v[4] = (_Float16)f1.x; v[5] = (_Float16)f1.y;
        v[6] = (_Float16)f1.z; v[7] = (_Float16)f1.w;
        return v;
    } else {
        return *(const half8*)p;
    }
}

// H[N,BN] (fp16) = X[N,K] @ W[K,BN]. Wave owns 32-col group; B loaded once
// (loop-invariant, fp32 W cvt in-register); grid-stride over 16-row slabs
// with next-slab A prefetch. No LDS, no barriers.
template <int K, int BN, typename SRC>
__device__ __forceinline__ void gemm_work(const SRC* __restrict__ X,
                                          const float* __restrict__ W,
                                          _Float16* __restrict__ H, int N,
                                          int w, int totalWaves) {
    constexpr int NC = K / 32;        // k-chunks
    constexpr int CG = BN / 32;       // col groups (waves per slab)
    const int lane = threadIdx.x & 63;
    const int quad = lane >> 4;
    const int m = lane & 15;
    const int cg = w & (CG - 1);
    const int nslab = N >> 4;         // N multiple of 16
    const int stride = totalWaves / CG;
    int slab = w / CG;
    if (slab >= nslab) return;
    const int n0 = cg * 32;

    half8 b0[NC], b1[NC];
#pragma unroll
    for (int c = 0; c < NC; ++c) {
#pragma unroll
        for (int j = 0; j < 8; ++j) {
            int k = c * 32 + quad * 8 + j;
            b0[c][j] = (_Float16)W[(size_t)k * BN + n0 + m];
            b1[c][j] = (_Float16)W[(size_t)k * BN + n0 + 16 + m];
        }
    }

    half8 a[NC];
#pragma unroll
    for (int c = 0; c < NC; ++c)
        a[c] = loadA(&X[(size_t)(slab * 16 + m) * K + c * 32 + quad * 8]);

    while (true) {
        const int next = slab + stride;
        half8 an[NC];
        if (next < nslab) {
#pragma unroll
            for (int c = 0; c < NC; ++c)
                an[c] = loadA(&X[(size_t)(next * 16 + m) * K + c * 32 + quad * 8]);
        }

        floatx4 acc0 = (floatx4){0.f, 0.f, 0.f, 0.f};
        floatx4 acc1 = (floatx4){0.f, 0.f, 0.f, 0.f};
#pragma unroll
        for (int c = 0; c < NC; ++c) {
            acc0 = __builtin_amdgcn_mfma_f32_16x16x32_f16(a[c], b0[c], acc0, 0, 0, 0);
            acc1 = __builtin_amdgcn_mfma_f32_16x16x32_f16(a[c], b1[c], acc1, 0, 0, 0);
        }

        const int r0 = slab * 16 + quad * 4;
#pragma unroll
        for (int r = 0; r < 4; ++r) {
            H[(size_t)(r0 + r) * BN + n0 + m]      = (_Float16)acc0[r];
            H[(size_t)(r0 + r) * BN + n0 + 16 + m] = (_Float16)acc1[r];
        }

        if (next >= nslab) break;
        slab = next;
#pragma unroll
        for (int c = 0; c < NC; ++c) a[c] = an[c];
    }
}

// ------------------------ fused gemm1 + work-stealing histogram ------------
// Blocks [0,gB): gemm1 first, then join stealing. Blocks [gB,..): steal from
// t=0. Chunk = 64 edges per wave via global atomic counter.
__global__ __launch_bounds__(256) void hist_gemm1_kernel(
        const float* __restrict__ x, const float* __restrict__ W1,
        _Float16* __restrict__ h1, int N,
        const int* __restrict__ ei, const float* __restrict__ ew,
        unsigned long long* __restrict__ pk, int* __restrict__ rank, int E,
        int* __restrict__ ctr, int gB) {
    const int b = blockIdx.x;
    if (b < gB)
        gemm_work<D0, D1, float>(x, W1, h1, N, b * 4 + (threadIdx.x >> 6), gB * 4);

    const int lane = threadIdx.x & 63;
    const int nChunks = (E + 63) >> 6;
    for (;;) {
        int c = 0;
        if (lane == 0) c = atomicAdd(ctr, 1);
        c = __shfl(c, 0);
        if (c >= nChunks) break;
        int e = c * 64 + lane;
        if (e < E) {
            int col = ei[E + e];
            unsigned int wfix = (unsigned int)(ew[e] * FIX_SCALE + 0.5f);
            unsigned long long old =
                atomicAdd(&pk[col], (1ULL << 32) | (unsigned long long)wfix);
            rank[e] = (int)(old >> 32);
        }
    }
}

// ------------------------------------------------------ standalone gemms ---
template <int K, int BN, typename SRC>
__global__ __launch_bounds__(256) void mfma_gemm(const SRC* __restrict__ X,
                                                 const float* __restrict__ W,
                                                 _Float16* __restrict__ H, int N) {
    gemm_work<K, BN, SRC>(X, W, H, N, blockIdx.x * 4 + (threadIdx.x >> 6), gridDim.x * 4);
}

// --------------------------------------------- 2-phase exclusive scan ------
__global__ __launch_bounds__(256) void scan_reduce(const unsigned long long* __restrict__ pk,
                                                   float* __restrict__ dinv,
                                                   int* __restrict__ cnt,
                                                   int* __restrict__ blockSum, int N) {
    __shared__ int s[256];
    const int t = threadIdx.x;
    const int i = blockIdx.x * 256 + t;
    int v = 0;
    if (i < N) {
        unsigned long long p = pk[i];
        float d = (float)(unsigned int)(p & 0xffffffffULL) * FIX_INV + 1.0f;  // +1 self-loop
        dinv[i] = rsqrtf(d);
        v = (int)(p >> 32);
        cnt[i] = v;
    }
    s[t] = v;
    __syncthreads();
#pragma unroll
    for (int off = 128; off > 0; off >>= 1) {
        if (t < off) s[t] += s[t + off];
        __syncthreads();
    }
    if (t == 0) blockSum[blockIdx.x] = s[0];
}

__global__ __launch_bounds__(256) void scan_apply(const int* __restrict__ cnt,
                                                  const int* __restrict__ blockSum,
                                                  int* __restrict__ row_ptr, int N, int B) {
    __shared__ int bs[256];
    __shared__ int s[256];
    const int t = threadIdx.x;
    bs[t] = (t < B) ? blockSum[t] : 0;
    __syncthreads();
#pragma unroll
    for (int off = 1; off < 256; off <<= 1) {
        int u = (t >= off) ? bs[t - off] : 0;
        __syncthreads();
        bs[t] += u;
        __syncthreads();
    }
    const int myOff = (blockIdx.x > 0) ? bs[blockIdx.x - 1] : 0;
    const int i = blockIdx.x * 256 + t;
    const int v = (i < N) ? cnt[i] : 0;
    s[t] = v;
    __syncthreads();
#pragma unroll
    for (int off = 1; off < 256; off <<= 1) {
        int u = (t >= off) ? s[t - off] : 0;
        __syncthreads();
        s[t] += u;
        __syncthreads();
    }
    if (i < N) row_ptr[i] = s[t] - v + myOff;
    if (blockIdx.x == 0 && t == 0) row_ptr[N] = bs[B - 1];
}

// ------------------------------------------------- bucket fill (CSR) -------
__global__ void fill_kernel(const int* __restrict__ ei, const float* __restrict__ ew,
                            const float* __restrict__ dinv,
                            const int* __restrict__ row_ptr, const int* __restrict__ rank,
                            int2* __restrict__ pairs, int E) {
    int e = blockIdx.x * blockDim.x + threadIdx.x;
    if (e < E) {
        int r = ei[e];
        int c = ei[E + e];
        float w = dinv[r] * ew[e] * dinv[c];
        pairs[row_ptr[c] + rank[e]] = make_int2(r, __float_as_int(w));
    }
}

// -------------------------------------------- fused aggregate + epilogue ----
// Software-pipelined: pairs 4 ahead, H-rows 3 ahead (clamped, branch-free).
template <int D, typename OUT>
__global__ __launch_bounds__(256) void agg_kernel(const _Float16* __restrict__ H,
                                                  const int* __restrict__ row_ptr,
                                                  const int2* __restrict__ pairs,
                                                  const float* __restrict__ dinv,
                                                  const float* __restrict__ bias,
                                                  OUT* __restrict__ out, int N) {
    constexpr int TPN = D / 8;        // threads per node (8 halves = 16B each)
    constexpr int NPB = 256 / TPN;    // nodes per block
    const int tid = threadIdx.x;
    const int g = tid / TPN;
    const int lane = tid % TPN;
    const int node = blockIdx.x * NPB + g;
    if (node >= N) return;

    const int beg = row_ptr[node];
    const int end = row_ptr[node + 1];
    float acc[8];
#pragma unroll
    for (int j = 0; j < 8; ++j) acc[j] = 0.0f;

    if (end > beg) {
        const int last = end - 1;
        int2 p0 = pairs[beg];
        int2 p1 = pairs[min(beg + 1, last)];
        int2 p2 = pairs[min(beg + 2, last)];
        int2 p3 = pairs[min(beg + 3, last)];
        half8 u0 = *(const half8*)&H[(size_t)p0.x * D + lane * 8];
        half8 u1 = *(const half8*)&H[(size_t)p1.x * D + lane * 8];
        half8 u2 = *(const half8*)&H[(size_t)p2.x * D + lane * 8];
        for (int k = beg; k < end; ++k) {
            int2 p4 = pairs[min(k + 4, last)];
            half8 u3 = *(const half8*)&H[(size_t)p3.x * D + lane * 8];
            float w = __int_as_float(p0.y);
#pragma unroll
            for (int j = 0; j < 8; ++j) acc[j] = fmaf(w, (float)u0[j], acc[j]);
            p0 = p1; p1 = p2; p2 = p3; p3 = p4;
            u0 = u1; u1 = u2; u2 = u3;
        }
    }
    // self-loop + bias + relu
    float di = dinv[node];
    float d2 = di * di;
    {
        half8 u = *(const half8*)&H[(size_t)node * D + lane * 8];
#pragma unroll
        for (int j = 0; j < 8; ++j) acc[j] = fmaf(d2, (float)u[j], acc[j]);
    }
    float b[8];
    *(float4*)&b[0] = *(const float4*)&bias[lane * 8];
    *(float4*)&b[4] = *(const float4*)&bias[lane * 8 + 4];
#pragma unroll
    for (int j = 0; j < 8; ++j) acc[j] = fmaxf(acc[j] + b[j], 0.f);

    if constexpr (sizeof(OUT) == 2) {
        half8 o;
#pragma unroll
        for (int j = 0; j < 8; ++j) o[j] = (_Float16)acc[j];
        *(half8*)&out[(size_t)node * D + lane * 8] = o;
    } else {
        float* dst = (float*)&out[(size_t)node * D + lane * 8];
        *(float4*)&dst[0] = make_float4(acc[0], acc[1], acc[2], acc[3]);
        *(float4*)&dst[4] = make_float4(acc[4], acc[5], acc[6], acc[7]);
    }
}

// ---------------------------------------------------------------- launch ----
extern "C" void kernel_launch(void* const* d_in, const int* in_sizes, int n_in,
                              void* d_out, int out_size, void* d_ws, size_t ws_size,
                              hipStream_t stream) {
    const float* x   = (const float*)d_in[0];
    const int* ei    = (const int*)d_in[1];
    const float* ew  = (const float*)d_in[2];
    const float* W1  = (const float*)d_in[3];
    const float* b1  = (const float*)d_in[4];
    const float* W2  = (const float*)d_in[5];
    const float* b2  = (const float*)d_in[6];
    const float* W3  = (const float*)d_in[7];
    const float* b3  = (const float*)d_in[8];
    float* out = (float*)d_out;

    const int N = in_sizes[0] / D0;   // 50000
    const int E = in_sizes[2];        // 800000
    (void)n_in; (void)out_size; (void)ws_size;

    // ---- workspace carving ----
    char* ws = (char*)d_ws;
    size_t off = 0;
    auto carve = [&](size_t bytes) -> void* {
        void* p = (void*)(ws + off);
        off += (bytes + 255) & ~(size_t)255;
        return p;
    };
    unsigned long long* pk = (unsigned long long*)carve((size_t)N * 8);
    int*   ctr     = (int*)carve(256);               // steal counter (memset w/ pk)
    float* dinv    = (float*)carve((size_t)N * 4);
    int*   cnt     = (int*)carve((size_t)N * 4);
    int*   row_ptr = (int*)carve((size_t)(N + 1) * 4);
    int*   rank    = (int*)carve((size_t)E * 4);
    int*   bsum    = (int*)carve(256 * 4);
    int2*  pairs   = (int2*)carve((size_t)E * 8);
    _Float16* bufH = (_Float16*)carve((size_t)N * D1 * 2);  // h1/h2/h3
    _Float16* bufO = (_Float16*)carve((size_t)N * D1 * 2);  // out1/out2 (fp16)

    _Float16* h1   = bufH;               // N x 128 fp16
    _Float16* out1 = bufO;               // N x 128 fp16 ; x for layer 2
    _Float16* h2   = bufH;               // N x 64 fp16 (h1 dead)
    _Float16* out2 = bufO;               // N x 64 fp16 (out1 dead after gemm2)
    _Float16* h3   = bufH;               // N x 32 fp16 (h2 dead)

    const int eb = (E + 255) / 256;       // 3125
    const int scanB = (N + 255) / 256;    // 196 (must be <= 256)
    const int gB = 768;                   // gemm blocks (3/CU, 3072 waves)
    const int histB = 1024;               // dedicated hist-steal blocks

    // ---- fused: gemm1 + work-stealing histogram ----
    size_t pkBytes = (((size_t)N * 8 + 255) & ~(size_t)255) + 256;  // pk + ctr
    hipMemsetAsync(pk, 0, pkBytes, stream);
    hist_gemm1_kernel<<<gB + histB, 256, 0, stream>>>(
        x, W1, h1, N, ei, ew, pk, rank, E, ctr, gB);

    // ---- CSR build ----
    scan_reduce<<<scanB, 256, 0, stream>>>(pk, dinv, cnt, bsum, N);
    scan_apply<<<scanB, 256, 0, stream>>>(cnt, bsum, row_ptr, N, scanB);
    fill_kernel<<<eb, 256, 0, stream>>>(ei, ew, dinv, row_ptr, rank, pairs, E);

    // ---- layer 1 aggregate ----
    agg_kernel<D1, _Float16><<<(N + 15) / 16, 256, 0, stream>>>(h1, row_ptr, pairs, dinv, b1, out1, N);

    // ---- layer 2: 128 -> 64 ----
    mfma_gemm<D1, D2, _Float16><<<gB, 256, 0, stream>>>(out1, W2, h2, N);
    agg_kernel<D2, _Float16><<<(N + 31) / 32, 256, 0, stream>>>(h2, row_ptr, pairs, dinv, b2, out2, N);

    // ---- layer 3: 64 -> 32 ----
    mfma_gemm<D2, D3, _Float16><<<gB, 256, 0, stream>>>(out2, W3, h3, N);
    agg_kernel<D3, float><<<(N + 63) / 64, 256, 0, stream>>>(h3, row_ptr, pairs, dinv, b3, out, N);
}

// Round 15
// 265.223 us; speedup vs baseline: 1.7311x; 1.7311x over previous
//
#include <hip/hip_runtime.h>
#include <hip/hip_fp16.h>

// GCN encoder: 3x (GCNConv + ReLU), dims 256->128->64->32
// N=50000 nodes, E=800000 edges. edge_index delivered as int32 (harness).
// R2: CSR gather.  R4: packed deg+cnt atomic.  R5: fp16 H buffers.
// R6: MFMA gemms.  R7: atomic-free fill via rank.  R10: persistent-B gemm.
// R11: fused scan; pipelined agg.  R12: gemm1 fused with histogram (serial).
// R13: work-stealing counter FAILED (12500 serialized atomic grabs = 260us).
// R14: static role partition, INTERLEAVED by block index (b%5==0 -> gemm)
//      so both roles are co-resident from t=0 and HW-overlap (m114).

#define D0 256
#define D1 128
#define D2 64
#define D3 32

#define FIX_SCALE 16777216.0f           // 2^24 fixed-point for degree
#define FIX_INV   (1.0f / 16777216.0f)

typedef _Float16 half8 __attribute__((ext_vector_type(8)));
typedef float floatx4 __attribute__((ext_vector_type(4)));

// ------------------------------------------------------ gemm device core ---
template <typename SRC>
__device__ __forceinline__ half8 loadA(const SRC* __restrict__ p) {
    if constexpr (sizeof(SRC) == 4) {
        float4 f0 = *(const float4*)p;
        float4 f1 = *(const float4*)(p + 4);
        half8 v;
        v[0] = (_Float16)f0.x; v[1] = (_Float16)f0.y;
        v[2] = (_Float16)f0.z; v[3] = (_Float16)f0.w;
        v[4] = (_Float16)f1.x; v[5] = (_Float16)f1.y;
        v[6] = (_Float16)f1.z; v[7] = (_Float16)f1.w;
        return v;
    } else {
        return *(const half8*)p;
    }
}

// H[N,BN] (fp16) = X[N,K] @ W[K,BN]. Wave owns 32-col group; B loaded once
// (loop-invariant, fp32 W cvt in-register); grid-stride over 16-row slabs
// with next-slab A prefetch. No LDS, no barriers.
template <int K, int BN, typename SRC>
__device__ __forceinline__ void gemm_work(const SRC* __restrict__ X,
                                          const float* __restrict__ W,
                                          _Float16* __restrict__ H, int N,
                                          int w, int totalWaves) {
    constexpr int NC = K / 32;        // k-chunks
    constexpr int CG = BN / 32;       // col groups (waves per slab)
    const int lane = threadIdx.x & 63;
    const int quad = lane >> 4;
    const int m = lane & 15;
    const int cg = w & (CG - 1);
    const int nslab = N >> 4;         // N multiple of 16
    const int stride = totalWaves / CG;
    int slab = w / CG;
    if (slab >= nslab) return;
    const int n0 = cg * 32;

    half8 b0[NC], b1[NC];
#pragma unroll
    for (int c = 0; c < NC; ++c) {
#pragma unroll
        for (int j = 0; j < 8; ++j) {
            int k = c * 32 + quad * 8 + j;
            b0[c][j] = (_Float16)W[(size_t)k * BN + n0 + m];
            b1[c][j] = (_Float16)W[(size_t)k * BN + n0 + 16 + m];
        }
    }

    half8 a[NC];
#pragma unroll
    for (int c = 0; c < NC; ++c)
        a[c] = loadA(&X[(size_t)(slab * 16 + m) * K + c * 32 + quad * 8]);

    while (true) {
        const int next = slab + stride;
        half8 an[NC];
        if (next < nslab) {
#pragma unroll
            for (int c = 0; c < NC; ++c)
                an[c] = loadA(&X[(size_t)(next * 16 + m) * K + c * 32 + quad * 8]);
        }

        floatx4 acc0 = (floatx4){0.f, 0.f, 0.f, 0.f};
        floatx4 acc1 = (floatx4){0.f, 0.f, 0.f, 0.f};
#pragma unroll
        for (int c = 0; c < NC; ++c) {
            acc0 = __builtin_amdgcn_mfma_f32_16x16x32_f16(a[c], b0[c], acc0, 0, 0, 0);
            acc1 = __builtin_amdgcn_mfma_f32_16x16x32_f16(a[c], b1[c], acc1, 0, 0, 0);
        }

        const int r0 = slab * 16 + quad * 4;
#pragma unroll
        for (int r = 0; r < 4; ++r) {
            H[(size_t)(r0 + r) * BN + n0 + m]      = (_Float16)acc0[r];
            H[(size_t)(r0 + r) * BN + n0 + 16 + m] = (_Float16)acc1[r];
        }

        if (next >= nslab) break;
        slab = next;
#pragma unroll
        for (int c = 0; c < NC; ++c) a[c] = an[c];
    }
}

// ------------------- fused gemm1 + histogram, interleaved static roles -----
// Every 5th block (b%5==0, b/5<gB) runs gemm1; the rest run one 256-edge
// histogram chunk. Both roles co-resident from t=0 -> HW overlap.
__global__ __launch_bounds__(256) void hist_gemm1_kernel(
        const float* __restrict__ x, const float* __restrict__ W1,
        _Float16* __restrict__ h1, int N,
        const int* __restrict__ ei, const float* __restrict__ ew,
        unsigned long long* __restrict__ pk, int* __restrict__ rank, int E,
        int gB) {
    const int b = blockIdx.x;
    const int g = b / 5;
    const bool isGemm = (b % 5 == 0) && (g < gB);
    if (isGemm) {
        gemm_work<D0, D1, float>(x, W1, h1, N, g * 4 + (threadIdx.x >> 6), gB * 4);
    } else {
        const int nGemmBefore = min((b + 4) / 5, gB);
        const int h = b - nGemmBefore;          // hist block index, dense
        int e = h * 256 + threadIdx.x;
        if (e < E) {
            int col = ei[E + e];
            unsigned int wfix = (unsigned int)(ew[e] * FIX_SCALE + 0.5f);
            unsigned long long old =
                atomicAdd(&pk[col], (1ULL << 32) | (unsigned long long)wfix);
            rank[e] = (int)(old >> 32);
        }
    }
}

// ------------------------------------------------------ standalone gemms ---
template <int K, int BN, typename SRC>
__global__ __launch_bounds__(256) void mfma_gemm(const SRC* __restrict__ X,
                                                 const float* __restrict__ W,
                                                 _Float16* __restrict__ H, int N) {
    gemm_work<K, BN, SRC>(X, W, H, N, blockIdx.x * 4 + (threadIdx.x >> 6), gridDim.x * 4);
}

// --------------------------------------------- 2-phase exclusive scan ------
__global__ __launch_bounds__(256) void scan_reduce(const unsigned long long* __restrict__ pk,
                                                   float* __restrict__ dinv,
                                                   int* __restrict__ cnt,
                                                   int* __restrict__ blockSum, int N) {
    __shared__ int s[256];
    const int t = threadIdx.x;
    const int i = blockIdx.x * 256 + t;
    int v = 0;
    if (i < N) {
        unsigned long long p = pk[i];
        float d = (float)(unsigned int)(p & 0xffffffffULL) * FIX_INV + 1.0f;  // +1 self-loop
        dinv[i] = rsqrtf(d);
        v = (int)(p >> 32);
        cnt[i] = v;
    }
    s[t] = v;
    __syncthreads();
#pragma unroll
    for (int off = 128; off > 0; off >>= 1) {
        if (t < off) s[t] += s[t + off];
        __syncthreads();
    }
    if (t == 0) blockSum[blockIdx.x] = s[0];
}

__global__ __launch_bounds__(256) void scan_apply(const int* __restrict__ cnt,
                                                  const int* __restrict__ blockSum,
                                                  int* __restrict__ row_ptr, int N, int B) {
    __shared__ int bs[256];
    __shared__ int s[256];
    const int t = threadIdx.x;
    bs[t] = (t < B) ? blockSum[t] : 0;
    __syncthreads();
#pragma unroll
    for (int off = 1; off < 256; off <<= 1) {
        int u = (t >= off) ? bs[t - off] : 0;
        __syncthreads();
        bs[t] += u;
        __syncthreads();
    }
    const int myOff = (blockIdx.x > 0) ? bs[blockIdx.x - 1] : 0;
    const int i = blockIdx.x * 256 + t;
    const int v = (i < N) ? cnt[i] : 0;
    s[t] = v;
    __syncthreads();
#pragma unroll
    for (int off = 1; off < 256; off <<= 1) {
        int u = (t >= off) ? s[t - off] : 0;
        __syncthreads();
        s[t] += u;
        __syncthreads();
    }
    if (i < N) row_ptr[i] = s[t] - v + myOff;
    if (blockIdx.x == 0 && t == 0) row_ptr[N] = bs[B - 1];
}

// ------------------------------------------------- bucket fill (CSR) -------
__global__ void fill_kernel(const int* __restrict__ ei, const float* __restrict__ ew,
                            const float* __restrict__ dinv,
                            const int* __restrict__ row_ptr, const int* __restrict__ rank,
                            int2* __restrict__ pairs, int E) {
    int e = blockIdx.x * blockDim.x + threadIdx.x;
    if (e < E) {
        int r = ei[e];
        int c = ei[E + e];
        float w = dinv[r] * ew[e] * dinv[c];
        pairs[row_ptr[c] + rank[e]] = make_int2(r, __float_as_int(w));
    }
}

// -------------------------------------------- fused aggregate + epilogue ----
// Software-pipelined: pairs 4 ahead, H-rows 3 ahead (clamped, branch-free).
template <int D, typename OUT>
__global__ __launch_bounds__(256) void agg_kernel(const _Float16* __restrict__ H,
                                                  const int* __restrict__ row_ptr,
                                                  const int2* __restrict__ pairs,
                                                  const float* __restrict__ dinv,
                                                  const float* __restrict__ bias,
                                                  OUT* __restrict__ out, int N) {
    constexpr int TPN = D / 8;        // threads per node (8 halves = 16B each)
    constexpr int NPB = 256 / TPN;    // nodes per block
    const int tid = threadIdx.x;
    const int g = tid / TPN;
    const int lane = tid % TPN;
    const int node = blockIdx.x * NPB + g;
    if (node >= N) return;

    const int beg = row_ptr[node];
    const int end = row_ptr[node + 1];
    float acc[8];
#pragma unroll
    for (int j = 0; j < 8; ++j) acc[j] = 0.0f;

    if (end > beg) {
        const int last = end - 1;
        int2 p0 = pairs[beg];
        int2 p1 = pairs[min(beg + 1, last)];
        int2 p2 = pairs[min(beg + 2, last)];
        int2 p3 = pairs[min(beg + 3, last)];
        half8 u0 = *(const half8*)&H[(size_t)p0.x * D + lane * 8];
        half8 u1 = *(const half8*)&H[(size_t)p1.x * D + lane * 8];
        half8 u2 = *(const half8*)&H[(size_t)p2.x * D + lane * 8];
        for (int k = beg; k < end; ++k) {
            int2 p4 = pairs[min(k + 4, last)];
            half8 u3 = *(const half8*)&H[(size_t)p3.x * D + lane * 8];
            float w = __int_as_float(p0.y);
#pragma unroll
            for (int j = 0; j < 8; ++j) acc[j] = fmaf(w, (float)u0[j], acc[j]);
            p0 = p1; p1 = p2; p2 = p3; p3 = p4;
            u0 = u1; u1 = u2; u2 = u3;
        }
    }
    // self-loop + bias + relu
    float di = dinv[node];
    float d2 = di * di;
    {
        half8 u = *(const half8*)&H[(size_t)node * D + lane * 8];
#pragma unroll
        for (int j = 0; j < 8; ++j) acc[j] = fmaf(d2, (float)u[j], acc[j]);
    }
    float b[8];
    *(float4*)&b[0] = *(const float4*)&bias[lane * 8];
    *(float4*)&b[4] = *(const float4*)&bias[lane * 8 + 4];
#pragma unroll
    for (int j = 0; j < 8; ++j) acc[j] = fmaxf(acc[j] + b[j], 0.f);

    if constexpr (sizeof(OUT) == 2) {
        half8 o;
#pragma unroll
        for (int j = 0; j < 8; ++j) o[j] = (_Float16)acc[j];
        *(half8*)&out[(size_t)node * D + lane * 8] = o;
    } else {
        float* dst = (float*)&out[(size_t)node * D + lane * 8];
        *(float4*)&dst[0] = make_float4(acc[0], acc[1], acc[2], acc[3]);
        *(float4*)&dst[4] = make_float4(acc[4], acc[5], acc[6], acc[7]);
    }
}

// ---------------------------------------------------------------- launch ----
extern "C" void kernel_launch(void* const* d_in, const int* in_sizes, int n_in,
                              void* d_out, int out_size, void* d_ws, size_t ws_size,
                              hipStream_t stream) {
    const float* x   = (const float*)d_in[0];
    const int* ei    = (const int*)d_in[1];
    const float* ew  = (const float*)d_in[2];
    const float* W1  = (const float*)d_in[3];
    const float* b1  = (const float*)d_in[4];
    const float* W2  = (const float*)d_in[5];
    const float* b2  = (const float*)d_in[6];
    const float* W3  = (const float*)d_in[7];
    const float* b3  = (const float*)d_in[8];
    float* out = (float*)d_out;

    const int N = in_sizes[0] / D0;   // 50000
    const int E = in_sizes[2];        // 800000
    (void)n_in; (void)out_size; (void)ws_size;

    // ---- workspace carving ----
    char* ws = (char*)d_ws;
    size_t off = 0;
    auto carve = [&](size_t bytes) -> void* {
        void* p = (void*)(ws + off);
        off += (bytes + 255) & ~(size_t)255;
        return p;
    };
    unsigned long long* pk = (unsigned long long*)carve((size_t)N * 8);
    float* dinv    = (float*)carve((size_t)N * 4);
    int*   cnt     = (int*)carve((size_t)N * 4);
    int*   row_ptr = (int*)carve((size_t)(N + 1) * 4);
    int*   rank    = (int*)carve((size_t)E * 4);
    int*   bsum    = (int*)carve(256 * 4);
    int2*  pairs   = (int2*)carve((size_t)E * 8);
    _Float16* bufH = (_Float16*)carve((size_t)N * D1 * 2);  // h1/h2/h3
    _Float16* bufO = (_Float16*)carve((size_t)N * D1 * 2);  // out1/out2 (fp16)

    _Float16* h1   = bufH;               // N x 128 fp16
    _Float16* out1 = bufO;               // N x 128 fp16 ; x for layer 2
    _Float16* h2   = bufH;               // N x 64 fp16 (h1 dead)
    _Float16* out2 = bufO;               // N x 64 fp16 (out1 dead after gemm2)
    _Float16* h3   = bufH;               // N x 32 fp16 (h2 dead)

    const int eb = (E + 255) / 256;       // 3125 hist blocks
    const int scanB = (N + 255) / 256;    // 196 (must be <= 256)
    const int gB = 768;                   // gemm blocks (3/CU, 3072 waves)

    // ---- fused: gemm1 + histogram, interleaved roles ----
    hipMemsetAsync(pk, 0, (size_t)N * 8, stream);
    hist_gemm1_kernel<<<gB + eb, 256, 0, stream>>>(
        x, W1, h1, N, ei, ew, pk, rank, E, gB);

    // ---- CSR build ----
    scan_reduce<<<scanB, 256, 0, stream>>>(pk, dinv, cnt, bsum, N);
    scan_apply<<<scanB, 256, 0, stream>>>(cnt, bsum, row_ptr, N, scanB);
    fill_kernel<<<eb, 256, 0, stream>>>(ei, ew, dinv, row_ptr, rank, pairs, E);

    // ---- layer 1 aggregate ----
    agg_kernel<D1, _Float16><<<(N + 15) / 16, 256, 0, stream>>>(h1, row_ptr, pairs, dinv, b1, out1, N);

    // ---- layer 2: 128 -> 64 ----
    mfma_gemm<D1, D2, _Float16><<<gB, 256, 0, stream>>>(out1, W2, h2, N);
    agg_kernel<D2, _Float16><<<(N + 31) / 32, 256, 0, stream>>>(h2, row_ptr, pairs, dinv, b2, out2, N);

    // ---- layer 3: 64 -> 32 ----
    mfma_gemm<D2, D3, _Float16><<<gB, 256, 0, stream>>>(out2, W3, h3, N);
    agg_kernel<D3, float><<<(N + 63) / 64, 256, 0, stream>>>(h3, row_ptr, pairs, dinv, b3, out, N);
}